// Round 15
// baseline (235.927 us; speedup 1.0000x reference)
//
#include <hip/hip_runtime.h>
#include <hip/hip_bf16.h>
#include <math.h>

#define B_   8
#define T_   2048
#define DIN  1024
#define H_   1024
#define G_   16
#define M_   (B_ * T_)   // 16384
#define NCH  (B_ * H_)   // 8192 channels
#define SUB  32          // timesteps per scan subchunk
#define NSUB (T_ / SUB)  // 64 subchunks per channel

#define LN2f     0.69314718056f
#define LOG2Ef   1.44269504089f

typedef __bf16 bf16_t;
typedef unsigned char u8;
typedef long long i64;
typedef i64   i64x2  __attribute__((ext_vector_type(2)));
typedef float f32x4  __attribute__((ext_vector_type(4)));
typedef unsigned short u16x2 __attribute__((ext_vector_type(2)));
typedef unsigned short u16x8 __attribute__((ext_vector_type(8)));

__device__ __forceinline__ float bf2f(unsigned short u) {
    union { unsigned int i; float f; } c; c.i = ((unsigned int)u) << 16; return c.f;
}
__device__ __forceinline__ unsigned short f2bf(float f) {
    union { __bf16 h; unsigned short u; } c; c.h = (__bf16)f; return c.u;
}
__device__ __forceinline__ float fexp2(float x) { return __builtin_amdgcn_exp2f(x); }
__device__ __forceinline__ float flog2(float x) { return __builtin_amdgcn_logf(x); }

__device__ __forceinline__ float log_g_dev(float x) {
    return (x >= 0.f) ? LN2f * flog2(x + 0.5f)
                      : (x - LN2f * flog2(1.f + fexp2(x * LOG2Ef)));
}
__device__ __forceinline__ float logaddexp_f(float a, float b) {
    float m = fmaxf(a, b);
    float d = -fabsf(a - b);                 // <= 0 (or -inf)
    return m + LN2f * flog2(1.f + fexp2(d * LOG2Ef));
}

// async global->LDS, 16 bytes per lane; LDS dest = uniform base + lane*16
__device__ __forceinline__ void async16(void* lds, const void* g) {
    __builtin_amdgcn_global_load_lds(
        (const __attribute__((address_space(1))) void*)g,
        (__attribute__((address_space(3))) void*)lds, 16, 0, 0);
}

// ---------------------------------------------------------------------------
// fp32 -> fp8 e4m3 bulk convert for X, Wz, Wh (8 elems/thread) WITH k-block
// permutation: within each row's 64-byte k-block, 8B granule
//   o = half*4 + kq  ->  p = kq*2 + half     (half = k-bytes 0-31 vs 32-63)
// so the 16B LDS slot for k-quad kq holds [ks=0 8B | ks=1 8B] -> fragment
// reads become a single conflict-free ds_read_b128 at lane*16.
// ---------------------------------------------------------------------------
#define NX8 (M_ * DIN / 8)
#define NW8 (H_ * DIN / 8)

__global__ __launch_bounds__(256) void cvt_all(
    const float* __restrict__ x,  u8* __restrict__ Xb,
    const float* __restrict__ wz, u8* __restrict__ Wzb,
    const float* __restrict__ wh, u8* __restrict__ Whb)
{
    int i = blockIdx.x * 256 + threadIdx.x;
    const float* src; u8* dst;
    if (i < NX8)            { src = x;  dst = Xb; }
    else if (i < NX8 + NW8) { src = wz; dst = Wzb; i -= NX8; }
    else                    { src = wh; dst = Whb; i -= NX8 + NW8; }
    float4 a = ((const float4*)src)[2 * i];
    float4 b = ((const float4*)src)[2 * i + 1];
    int lo = __builtin_amdgcn_cvt_pk_fp8_f32(a.x, a.y, 0,  false);
    lo     = __builtin_amdgcn_cvt_pk_fp8_f32(a.z, a.w, lo, true);
    int hi = __builtin_amdgcn_cvt_pk_fp8_f32(b.x, b.y, 0,  false);
    hi     = __builtin_amdgcn_cvt_pk_fp8_f32(b.z, b.w, hi, true);
    int2 o8; o8.x = lo; o8.y = hi;
    const int o = i & 7;                        // 8B slot in 64B k-block
    const int p = ((o & 3) << 1) | (o >> 2);    // permuted slot
    ((int2*)dst)[(i & ~7) | p] = o8;
}

// ---------------------------------------------------------------------------
// fp8 MFMA GEMM: 128x64 tile, BK=64 bytes, 16 K-iters, 2-stage LDS pipeline,
// one __syncthreads per iter, 32 MFMA/iter. Fragment reads are single
// ds_read_b128 at (tile*1024 + lane*16) thanks to the cvt permutation:
// lo 8B = k-step 0, hi 8B = k-step 1. Conflict-free (sequential lane->slot).
// Fused epilogue: coalesced stores via LDS transpose + in-block group-norm
// (BN == 64 == one group) -> Nbuf [M,16].
//   Cb = raw -softplus(k) (bf16) ; Vb = -softplus(-k)+log_g(q) (bf16, d_out)
// ---------------------------------------------------------------------------
#define BM 128
#define BN 64
#define BKB 64          // k bytes per stage
#define STRD 72         // output-transpose stride (elems)
#define STG_Z 8192      // byte offset of Z within stage
#define STG_H 12288     // byte offset of H within stage
#define STG_BYTES 16384 // bytes per stage

__global__ __launch_bounds__(256, 4) void gemm_mfma(
    const u8* __restrict__ Xb,
    const u8* __restrict__ Wzb, const float* __restrict__ bz,
    const u8* __restrict__ Whb, const float* __restrict__ bh,
    bf16_t* __restrict__ Cb, bf16_t* __restrict__ Vb,
    float* __restrict__ Nbuf)
{
    __shared__ __align__(16) char smem[33792];      // 32 KB staging + 1 KB sN
    char* sbase = smem;
    unsigned short* sT = (unsigned short*)smem;     // 18 KB, aliases staging
    float* sN = (float*)(smem + 32768);             // [2][BM]

    const int tid  = threadIdx.x;
    const int m0   = blockIdx.x * BM;
    const int n0   = blockIdx.y * BN;
    const int lane = tid & 63;
    const int wave = tid >> 6;
    const int wm = wave & 1, wn = wave >> 1;   // wave tile: rows wm*64, cols wn*32

    // staging: wave stages A m-tiles (wave*2, wave*2+1), Z/H n-tile (wave)
    const int srow   = lane & 15;
    const int scol16 = (lane >> 4) * 16;       // k-byte offset (permuted blocks)
    const size_t gA0 = (size_t)(m0 + wave * 32      + srow) * DIN + scol16;
    const size_t gA1 = (size_t)(m0 + wave * 32 + 16 + srow) * DIN + scol16;
    const size_t gB0 = (size_t)(n0 + wave * 16      + srow) * DIN + scol16;
    const int oA0 = (wave * 2    ) * 1024;
    const int oA1 = (wave * 2 + 1) * 1024;
    const int oZ0 = STG_Z + wave * 1024;
    const int oH0 = STG_H + wave * 1024;

    f32x4 dz[4][2], dh[4][2];
    #pragma unroll
    for (int i = 0; i < 4; ++i)
        #pragma unroll
        for (int j = 0; j < 2; ++j) { dz[i][j] = (f32x4)0.f; dh[i][j] = (f32x4)0.f; }

    // prologue: stage tile 0 into buf 0
    async16(sbase + oA0, Xb  + gA0);
    async16(sbase + oA1, Xb  + gA1);
    async16(sbase + oZ0, Wzb + gB0);
    async16(sbase + oH0, Whb + gB0);

    const int lane16 = lane * 16;
    const int kIters = DIN / BKB;    // 16
    for (int it = 0; it < kIters; ++it) {
        char* cur = sbase + (it & 1) * STG_BYTES;
        char* nxt = sbase + ((it & 1) ^ 1) * STG_BYTES;
        __syncthreads();             // drains cur's loads; prev reads of nxt done
        if (it + 1 < kIters) {
            const int k1 = (it + 1) * BKB;
            async16(nxt + oA0, Xb  + gA0 + k1);
            async16(nxt + oA1, Xb  + gA1 + k1);
            async16(nxt + oZ0, Wzb + gB0 + k1);
            async16(nxt + oH0, Whb + gB0 + k1);
        }
        i64x2 af[4], bz8[2], bh8[2];
        #pragma unroll
        for (int i = 0; i < 4; ++i)
            af[i] = *(const i64x2*)(cur + (wm * 4 + i) * 1024 + lane16);
        #pragma unroll
        for (int j = 0; j < 2; ++j) {
            bz8[j] = *(const i64x2*)(cur + STG_Z + (wn * 2 + j) * 1024 + lane16);
            bh8[j] = *(const i64x2*)(cur + STG_H + (wn * 2 + j) * 1024 + lane16);
        }
        #pragma unroll
        for (int ks = 0; ks < 2; ++ks)
            #pragma unroll
            for (int i = 0; i < 4; ++i)
                #pragma unroll
                for (int j = 0; j < 2; ++j) {
                    dz[i][j] = __builtin_amdgcn_mfma_f32_16x16x32_fp8_fp8(af[i][ks], bz8[j][ks], dz[i][j], 0, 0, 0);
                    dh[i][j] = __builtin_amdgcn_mfma_f32_16x16x32_fp8_fp8(af[i][ks], bh8[j][ks], dh[i][j], 0, 0, 0);
                }
    }
    __syncthreads();                 // all LDS reads done; sT may alias staging

    // ---- epilogue. D layout: col = lane&15, row = (lane>>4)*4 + reg ----
    const int cq = lane >> 4;
    const int cn = lane & 15;
    float lc0v[2][4][4];
    float ssum[4][4];
    #pragma unroll
    for (int i = 0; i < 4; ++i)
        #pragma unroll
        for (int rr = 0; rr < 4; ++rr) ssum[i][rr] = 0.f;

    #pragma unroll
    for (int j = 0; j < 2; ++j) {
        const int col = wn * 32 + j * 16 + cn;          // 0..63 in block
        const float bzv = bz[n0 + col];
        const float bhv = bh[n0 + col];
        #pragma unroll
        for (int i = 0; i < 4; ++i) {
            const int lrow = wm * 64 + i * 16 + cq * 4; // 0..127 in block
            #pragma unroll
            for (int rr = 0; rr < 4; ++rr) {
                float k = dz[i][j][rr] + bzv;
                float q = dh[i][j][rr] + bhv;
                float t   = LN2f * flog2(1.f + fexp2(-fabsf(k) * LOG2Ef));
                float lz  = fminf(k, 0.f) - t;
                float lc0 = -fmaxf(k, 0.f) - t;
                lc0v[j][i][rr] = lc0;
                ssum[i][rr] += lc0 * lc0;
                sT[(lrow + rr) * STRD + col] = f2bf(lz + log_g_dev(q));
            }
        }
    }
    // group-norm partial: reduce over the 16 cn-lanes (lane bits 0..3)
    #pragma unroll
    for (int i = 0; i < 4; ++i)
        #pragma unroll
        for (int rr = 0; rr < 4; ++rr) {
            float v = ssum[i][rr];
            v += __shfl_xor(v, 1);
            v += __shfl_xor(v, 2);
            v += __shfl_xor(v, 4);
            v += __shfl_xor(v, 8);
            ssum[i][rr] = v;
        }
    if (cn == 0) {
        #pragma unroll
        for (int i = 0; i < 4; ++i)
            #pragma unroll
            for (int rr = 0; rr < 4; ++rr)
                sN[wn * BM + wm * 64 + i * 16 + cq * 4 + rr] = ssum[i][rr];
    }
    __syncthreads();                 // sT(lv) + sN complete

    // coalesced V store (16B/lane) + Nbuf
    const int trow = tid >> 3;           // 0..31
    const int tc8  = (tid & 7) * 8;      // 0,8,..,56
    #pragma unroll
    for (int p = 0; p < 4; ++p) {
        const int row = p * 32 + trow;
        u16x8 v = *(const u16x8*)&sT[row * STRD + tc8];
        *(u16x8*)((unsigned short*)Vb + (size_t)(m0 + row) * H_ + n0 + tc8) = v;
    }
    if (tid < BM) {
        float nrm = sqrtf(sN[tid] + sN[BM + tid]);
        Nbuf[(size_t)(m0 + tid) * G_ + blockIdx.y] = nrm;
    }
    __syncthreads();                 // sT reads done

    // stage lc0 and store Cb the same way
    #pragma unroll
    for (int j = 0; j < 2; ++j) {
        const int col = wn * 32 + j * 16 + cn;
        #pragma unroll
        for (int i = 0; i < 4; ++i) {
            const int lrow = wm * 64 + i * 16 + cq * 4;
            #pragma unroll
            for (int rr = 0; rr < 4; ++rr)
                sT[(lrow + rr) * STRD + col] = f2bf(lc0v[j][i][rr]);
        }
    }
    __syncthreads();
    #pragma unroll
    for (int p = 0; p < 4; ++p) {
        const int row = p * 32 + trow;
        u16x8 v = *(const u16x8*)&sT[row * STRD + tc8];
        *(u16x8*)((unsigned short*)Cb + (size_t)(m0 + row) * H_ + n0 + tc8) = v;
    }
}

// ---------------------------------------------------------------------------
// Shared helper: computes fac[t][g] for rows (b, subg*SUB + t) in LDS.
// ---------------------------------------------------------------------------
__device__ __forceinline__ void block_fac(
    const float* __restrict__ Nbuf, int b, int subg, float (*sFac)[G_])
{
    const int tid = threadIdx.x;
    if (tid < SUB) {
        const size_t row = (size_t)(b * T_ + subg * SUB + tid);
        const float4* np = (const float4*)(Nbuf + row * G_);
        float4 n4[4] = {np[0], np[1], np[2], np[3]};
        float* n = (float*)n4;
        float mx = n[0];
        #pragma unroll
        for (int g = 1; g < G_; ++g) mx = fmaxf(mx, n[g]);
        float se = 0.f;
        #pragma unroll
        for (int g = 0; g < G_; ++g) se += fexp2((n[g] - mx) * LOG2Ef);
        const float lse = mx + LN2f * flog2(se);
        #pragma unroll
        for (int g = 0; g < G_; ++g) sFac[tid][g] = (n[g] - lse) / n[g];
    }
    __syncthreads();
}

// ---------------------------------------------------------------------------
// Phase 1: subchunk summaries. 2 channels/thread, 512 ch/block,
// grid (2*B, NSUB) = 1024 blocks (4 blocks/CU).
// ---------------------------------------------------------------------------
__global__ __launch_bounds__(256) void scan_sum(
    const bf16_t* __restrict__ Cb, const bf16_t* __restrict__ Vb,
    const float* __restrict__ Nbuf, float2* __restrict__ Sb)
{
    __shared__ float sFac[SUB][G_];
    const int bx   = blockIdx.x;              // 0..2B-1
    const int b    = bx >> 1;
    const int half = bx & 1;
    const int subg = blockIdx.y;
    block_fac(Nbuf, b, subg, sFac);

    const int tid = threadIdx.x;
    const int h0c = half * 512 + tid * 2;     // 0..1022
    const int g   = h0c >> 6;
    const int ch0 = b * H_ + h0c;

    size_t idx = ((size_t)b * T_ + (size_t)subg * SUB) * H_ + h0c;
    float A[2], Bv[2];
    #pragma unroll
    for (int e = 0; e < 2; ++e) { A[e] = 0.f; Bv[e] = -INFINITY; }

    #pragma unroll 4
    for (int t = 0; t < SUB; ++t) {
        u16x2 c2 = *(const u16x2*)((const unsigned short*)Cb + idx);
        u16x2 v2 = *(const u16x2*)((const unsigned short*)Vb + idx);
        float fac = sFac[t][g];
        #pragma unroll
        for (int e = 0; e < 2; ++e) {
            float c = bf2f(c2[e]) * fac;
            A[e] += c;
            Bv[e] = logaddexp_f(Bv[e] + c, bf2f(v2[e]));
        }
        idx += H_;
    }
    float2* sp = Sb + (size_t)subg * NCH + ch0;
    #pragma unroll
    for (int e = 0; e < 2; ++e) { float2 o; o.x = A[e]; o.y = Bv[e]; sp[e] = o; }
}

// ---------------------------------------------------------------------------
// Phase 2: seed recompute (prefix over Sb k < subg from log_g(h0)), then
// 32-step replay + exp output. Same grid as scan_sum.
// ---------------------------------------------------------------------------
__global__ __launch_bounds__(256) void scan_out(
    const bf16_t* __restrict__ Cb, bf16_t* Vb /* == d_out */,
    const float* __restrict__ Nbuf, const float2* __restrict__ Sb,
    const float* __restrict__ h0)
{
    __shared__ float sFac[SUB][G_];
    const int bx   = blockIdx.x;
    const int b    = bx >> 1;
    const int half = bx & 1;
    const int subg = blockIdx.y;
    block_fac(Nbuf, b, subg, sFac);

    const int tid = threadIdx.x;
    const int h0c = half * 512 + tid * 2;
    const int g   = h0c >> 6;
    const int ch0 = b * H_ + h0c;

    // seed: s = log_g(h0), then compose summaries 0..subg-1
    float s[2];
    {
        float2 hv = *(const float2*)(h0 + ch0);
        s[0] = log_g_dev(hv.x); s[1] = log_g_dev(hv.y);
    }
    for (int k = 0; k < subg; ++k) {
        const float2* sp = Sb + (size_t)k * NCH + ch0;
        float2 ab0 = sp[0];
        float2 ab1 = sp[1];
        s[0] = logaddexp_f(s[0] + ab0.x, ab0.y);
        s[1] = logaddexp_f(s[1] + ab1.x, ab1.y);
    }

    size_t idx = ((size_t)b * T_ + (size_t)subg * SUB) * H_ + h0c;
    #pragma unroll 4
    for (int t = 0; t < SUB; ++t) {
        u16x2 c2 = *(const u16x2*)((const unsigned short*)Cb + idx);
        u16x2 v2 = *(const u16x2*)((const unsigned short*)Vb + idx);
        float fac = sFac[t][g];
        u16x2 o2;
        #pragma unroll
        for (int e = 0; e < 2; ++e) {
            float c = bf2f(c2[e]) * fac;
            s[e] = logaddexp_f(s[e] + c, bf2f(v2[e]));
            o2[e] = f2bf(fexp2(fminf(s[e], 88.f) * LOG2Ef));   // finite
        }
        *(u16x2*)((unsigned short*)Vb + idx) = o2;
        idx += H_;
    }
}

// ---------------------------------------------------------------------------
extern "C" void kernel_launch(void* const* d_in, const int* in_sizes, int n_in,
                              void* d_out, int out_size, void* d_ws, size_t ws_size,
                              hipStream_t stream)
{
    const float* x   = (const float*)d_in[0];
    const float* h0  = (const float*)d_in[1];
    const float* Wz  = (const float*)d_in[2];
    const float* bz  = (const float*)d_in[3];
    const float* Wh  = (const float*)d_in[4];
    const float* bh  = (const float*)d_in[5];

    bf16_t* out = (bf16_t*)d_out;                                 // [B,T,H] bf16
    char*   ws  = (char*)d_ws;
    bf16_t* Cb  = (bf16_t*)ws;                                    // 33.5 MB raw lc0
    float2* Sb  = (float2*)(ws + (size_t)M_ * H_ * 2);            //  4.0 MB (A,B)
    u8*     Xb  = (u8*)((char*)Sb + (size_t)NSUB * NCH * 8);      // 16.8 MB fp8
    u8*     Wzb = Xb + (size_t)M_ * DIN;                          //  1.0 MB fp8
    u8*     Whb = Wzb + (size_t)H_ * DIN;                         //  1.0 MB fp8
    float*  Nb  = (float*)(Whb + (size_t)H_ * DIN);               //  1.0 MB norms

    cvt_all<<<NX8 / 256 + 2 * (NW8 / 256), 256, 0, stream>>>(x, Xb, Wz, Wzb, Wh, Whb);
    gemm_mfma<<<dim3(M_ / BM, H_ / BN), 256, 0, stream>>>(Xb, Wzb, bz, Whb, bh, Cb, out, Nb);
    scan_sum<<<dim3(2 * B_, NSUB), 256, 0, stream>>>(Cb, out, Nb, Sb);
    scan_out<<<dim3(2 * B_, NSUB), 256, 0, stream>>>(Cb, out, Nb, Sb, h0);
}